// Round 6
// baseline (205.780 us; speedup 1.0000x reference)
//
#include <hip/hip_runtime.h>
#include <math.h>
#include <float.h>

// Problem constants
#define NTOK 65536
#define NCB  4
#define MCODE 512
#define DIM  64

#define QST_SIZE (NTOK * NCB * DIM)        // 16777216
#define IDX_OFF  (QST_SIZE + 3)            // 16777219

// Tiles: 4 waves/block, each wave owns 32 tokens (one 32-wide MFMA column tile)
#define TOK_TILE  128

// ws layout (bytes):
//   ehf f16[4*16*4*512] @ 0        (262144)  hi half of 512*e, MFMA-fragment order
//   elf f16[4*16*4*512] @ 262144   (262144)  lo half, fragment order
//   d0p f32[2048]       @ 524288   (8192)    -256 * sum(e^2)  (acc C-init)
//   counts int[2048]    @ 532480   (8192)
//   lossSum f32         @ 540672
#define WS_EH 0
#define WS_EL 262144
#define WS_D0 524288
#define WS_CNT 532480
#define WS_LOSS 540672

typedef _Float16 half8 __attribute__((ext_vector_type(8)));
typedef float floatx16 __attribute__((ext_vector_type(16)));

// ---- prep: fragment-order f16 hi/lo split of 512*e, d0p = -256*|e|^2 ----
// Fragment layout for A-operand of 32x32x16: for (c, nt, ch):
//   512 f16 block; lane = h*32 + row5 holds rows (nt*32+row5), k = ch*16 + h*8 + t
__global__ __launch_bounds__(256) void prep_kernel(const float* __restrict__ emb,
                                                   _Float16* __restrict__ ehf,
                                                   _Float16* __restrict__ elf,
                                                   float* __restrict__ d0p,
                                                   int* __restrict__ counts,
                                                   float* __restrict__ lossSum) {
    int row = blockIdx.x * 256 + threadIdx.x;   // 0..2047  (grid=8)
    if (row >= NCB * MCODE) return;
    const int c   = row >> 9;
    const int n   = row & 511;
    const int nt  = n >> 5;
    const int r5  = n & 31;
    const float* src = emb + (size_t)row * DIM;

    float s = 0.f;
#pragma unroll
    for (int ch = 0; ch < 4; ++ch) {
#pragma unroll
        for (int h = 0; h < 2; ++h) {
            half8 hv, lv;
#pragma unroll
            for (int t = 0; t < 8; ++t) {
                float e = src[ch * 16 + h * 8 + t];
                s += e * e;
                float f = e * 512.0f;
                _Float16 hi = (_Float16)f;
                float r = f - (float)hi;
                hv[t] = hi;
                lv[t] = (_Float16)r;
            }
            size_t off = ((size_t)((c * 16 + nt) * 4 + ch)) * 512 + (h * 32 + r5) * 8;
            *(half8*)(ehf + off) = hv;
            *(half8*)(elf + off) = lv;
        }
    }
    d0p[row] = -256.0f * s;
    counts[row] = 0;
    if (row == 0) *lossSum = 0.f;
}

// ---- main: 32x32x16 MFMA + per-lane argmin; A staged through dbuf LDS ----
// A = codes (block-shared LDS, 2 chunks per barrier interval), B = tokens
// (persistent, 32 VGPR). acc split into two 6-MFMA chains (k-chunks 0,1 vs
// 2,3); argmin split into 4 independent running maxima merged post-loop.
__global__ __launch_bounds__(256, 3) void vq_main(const float* __restrict__ x,
                                                  const float* __restrict__ emb,
                                                  const float* __restrict__ mask,
                                                  const _Float16* __restrict__ ehf,
                                                  const _Float16* __restrict__ elf,
                                                  const float* __restrict__ d0p,
                                                  int* __restrict__ counts,
                                                  float* __restrict__ lossSum,
                                                  float* __restrict__ outQ,
                                                  float* __restrict__ outIdx) {
    // [buf][chunk0: eh2048|el2048][chunk1: eh2048|el2048] = 2*16 KB = 32 KB
    __shared__ __align__(16) _Float16 As[2][8192];
    __shared__ __align__(16) float d0s[MCODE];       // 2 KB
    __shared__ int   Is[TOK_TILE];
    __shared__ float wls[4];

    const int tid  = threadIdx.x;
    const int c    = blockIdx.y;
    const int n0tk = blockIdx.x * TOK_TILE;
    const int lane = tid & 63;
    const int w    = tid >> 6;            // wave id 0..3
    const int l31  = lane & 31;           // token within wave tile / acc column
    const int hi   = lane >> 5;           // k-half for A/B, row-half for C
    const int hi4  = hi * 4;

    const _Float16* gEh = ehf + (size_t)c * (16 * 4 * 512);
    const _Float16* gEl = elf + (size_t)c * (16 * 4 * 512);

    // ---- stage interval 0 (chunks 0,1) + d0 (loads first, overlap B-build) ----
    float4 sh0 = *(const float4*)(gEh + tid * 8);
    float4 sl0 = *(const float4*)(gEl + tid * 8);
    float4 sh1 = *(const float4*)(gEh + 2048 + tid * 8);
    float4 sl1 = *(const float4*)(gEl + 2048 + tid * 8);
    float4 dstage;
    if (tid < 128) dstage = *(const float4*)(d0p + c * MCODE + tid * 4);

    // ---- persistent B fragments (x hi/lo) for this lane's token ----
    // B col = lane&31 = token; k = ch*16 + hi*8 + t
    half8 Bh[4], Bl[4];
    {
        const float* xr = x + (size_t)(n0tk + w * 32 + l31) * (NCB * DIM) + c * DIM + hi * 8;
#pragma unroll
        for (int ch = 0; ch < 4; ++ch) {
            float fv[8];
            *(float4*)(fv)     = *(const float4*)(xr + ch * 16);
            *(float4*)(fv + 4) = *(const float4*)(xr + ch * 16 + 4);
            half8 h8, l8;
#pragma unroll
            for (int t = 0; t < 8; ++t) {
                float f = fv[t];
                _Float16 hh = (_Float16)f;
                h8[t] = hh;
                l8[t] = (_Float16)(f - (float)hh);
            }
            Bh[ch] = h8;
            Bl[ch] = l8;
        }
    }

    *(float4*)((char*)&As[0][0]           + tid * 16) = sh0;
    *(float4*)((char*)&As[0][2048]        + tid * 16) = sl0;
    *(float4*)((char*)&As[0][4096]        + tid * 16) = sh1;
    *(float4*)((char*)&As[0][4096 + 2048] + tid * 16) = sl1;
    if (tid < 128) *(float4*)(&d0s[tid * 4]) = dstage;
    __syncthreads();

    // 4 independent argmin groups (r-group g covers rows nbase + 8g + 0..3)
    float gv[4];
    int   gn[4];
#pragma unroll
    for (int g = 0; g < 4; ++g) { gv[g] = -FLT_MAX; gn[g] = 0; }

    // ---- sweep 8 intervals x 2 chunks, dbuf LDS + 1-interval-ahead prefetch ----
    for (int j = 0; j < 8; ++j) {
        const int b = j & 1;

        // prefetch next interval's 2 chunks (latency hides under 24 MFMAs)
        float4 nh0, nl0, nh1, nl1;
        if (j < 7) {
            const int base = (2 * j + 2) * 2048;
            nh0 = *(const float4*)(gEh + base + tid * 8);
            nl0 = *(const float4*)(gEl + base + tid * 8);
            nh1 = *(const float4*)(gEh + base + 2048 + tid * 8);
            nl1 = *(const float4*)(gEl + base + 2048 + tid * 8);
        }

#pragma unroll
        for (int slot = 0; slot < 2; ++slot) {
            const int nt = 2 * j + slot;

            // A fragment reads from LDS (stride-1 b128, conflict-free)
            const _Float16* ah = &As[b][slot * 4096] + lane * 8;
            const _Float16* al = ah + 2048;
            half8 Ah0 = *(const half8*)(ah);
            half8 Ah1 = *(const half8*)(ah + 512);
            half8 Ah2 = *(const half8*)(ah + 1024);
            half8 Ah3 = *(const half8*)(ah + 1536);
            half8 Al0 = *(const half8*)(al);
            half8 Al1 = *(const half8*)(al + 512);
            half8 Al2 = *(const half8*)(al + 1024);
            half8 Al3 = *(const half8*)(al + 1536);

            // acc0: C-init = -256*|e|^2, k-chunks 0,1 ; acc1: C-init 0, k-chunks 2,3
            const float* dpt = &d0s[nt * 32 + hi4];
            float4 d40 = *(const float4*)(dpt);
            float4 d41 = *(const float4*)(dpt + 8);
            float4 d42 = *(const float4*)(dpt + 16);
            float4 d43 = *(const float4*)(dpt + 24);
            floatx16 acc0, acc1;
            acc0[0]  = d40.x; acc0[1]  = d40.y; acc0[2]  = d40.z; acc0[3]  = d40.w;
            acc0[4]  = d41.x; acc0[5]  = d41.y; acc0[6]  = d41.z; acc0[7]  = d41.w;
            acc0[8]  = d42.x; acc0[9]  = d42.y; acc0[10] = d42.z; acc0[11] = d42.w;
            acc0[12] = d43.x; acc0[13] = d43.y; acc0[14] = d43.z; acc0[15] = d43.w;
#pragma unroll
            for (int r = 0; r < 16; ++r) acc1[r] = 0.f;

            // two independent 6-MFMA chains
            acc1 = __builtin_amdgcn_mfma_f32_32x32x16_f16(Ah2, Bh[2], acc1, 0, 0, 0);
            acc0 = __builtin_amdgcn_mfma_f32_32x32x16_f16(Ah0, Bh[0], acc0, 0, 0, 0);
            acc1 = __builtin_amdgcn_mfma_f32_32x32x16_f16(Al2, Bh[2], acc1, 0, 0, 0);
            acc0 = __builtin_amdgcn_mfma_f32_32x32x16_f16(Al0, Bh[0], acc0, 0, 0, 0);
            acc1 = __builtin_amdgcn_mfma_f32_32x32x16_f16(Ah2, Bl[2], acc1, 0, 0, 0);
            acc0 = __builtin_amdgcn_mfma_f32_32x32x16_f16(Ah0, Bl[0], acc0, 0, 0, 0);
            acc1 = __builtin_amdgcn_mfma_f32_32x32x16_f16(Ah3, Bh[3], acc1, 0, 0, 0);
            acc0 = __builtin_amdgcn_mfma_f32_32x32x16_f16(Ah1, Bh[1], acc0, 0, 0, 0);
            acc1 = __builtin_amdgcn_mfma_f32_32x32x16_f16(Al3, Bh[3], acc1, 0, 0, 0);
            acc0 = __builtin_amdgcn_mfma_f32_32x32x16_f16(Al1, Bh[1], acc0, 0, 0, 0);
            acc1 = __builtin_amdgcn_mfma_f32_32x32x16_f16(Ah3, Bl[3], acc1, 0, 0, 0);
            acc0 = __builtin_amdgcn_mfma_f32_32x32x16_f16(Ah1, Bl[1], acc0, 0, 0, 0);

            // per-lane argmin: 4 independent groups, 4 serial compares each.
            // n(r) = nt*32 + hi4 + (r&3) + 8*(r>>2); within a group n is
            // strictly increasing over (nt, r&3) -> strict '>' keeps first-min.
            const int nbase = nt * 32 + hi4;
#pragma unroll
            for (int g = 0; g < 4; ++g) {
#pragma unroll
                for (int q = 0; q < 4; ++q) {
                    const int r = g * 4 + q;
                    float m = acc0[r] + acc1[r];
                    int   n = nbase + 8 * g + q;
                    if (m > gv[g]) { gv[g] = m; gn[g] = n; }
                }
            }
        }

        // write prefetched interval into the other buffer (vmcnt drain lands
        // here, after compute), one barrier per interval
        if (j < 7) {
            *(float4*)((char*)&As[b ^ 1][0]           + tid * 16) = nh0;
            *(float4*)((char*)&As[b ^ 1][2048]        + tid * 16) = nl0;
            *(float4*)((char*)&As[b ^ 1][4096]        + tid * 16) = nh1;
            *(float4*)((char*)&As[b ^ 1][4096 + 2048] + tid * 16) = nl1;
        }
        __syncthreads();
    }

    // ---- merge the 4 groups (value desc, index asc on ties) ----
    float maxv = gv[0];
    int   maxn = gn[0];
#pragma unroll
    for (int g = 1; g < 4; ++g) {
        if (gv[g] > maxv || (gv[g] == maxv && gn[g] < maxn)) { maxv = gv[g]; maxn = gn[g]; }
    }

    // ---- merge the two row-halves (lane <-> lane+32) ----
    {
        float ov = __shfl_xor(maxv, 32);
        int   on = __shfl_xor(maxn, 32);
        if (ov > maxv || (ov == maxv && on < maxn)) { maxv = ov; maxn = on; }
    }

    if (hi == 0) {
        Is[w * 32 + l31] = maxn;
        atomicAdd(&counts[c * MCODE + maxn], 1);
        outIdx[(size_t)(n0tk + w * 32 + l31) * NCB + c] = (float)maxn;
    }
    __syncthreads();

    // ---- quantized_st + loss (original fp32 emb + fp32 x for exactness) ----
    float lloss = 0.f;
#pragma unroll
    for (int i = 0; i < 8; ++i) {
        int q = tid + i * 256;
        int tok = q >> 4, d4 = q & 15;
        int idx = Is[tok];
        float mv = mask[(size_t)(n0tk + tok) * NCB + c];
        float4 e4 = *(const float4*)(emb + ((size_t)c * MCODE + idx) * DIM + d4 * 4);
        float4 x4 = *(const float4*)(x + (size_t)(n0tk + tok) * (NCB * DIM) + c * DIM + d4 * 4);
        float qx = e4.x * mv, qy = e4.y * mv, qz = e4.z * mv, qw = e4.w * mv;
        float4 o;
        o.x = x4.x + (qx - x4.x);
        o.y = x4.y + (qy - x4.y);
        o.z = x4.z + (qz - x4.z);
        o.w = x4.w + (qw - x4.w);
        *(float4*)(outQ + (size_t)(n0tk + tok) * (NCB * DIM) + c * DIM + d4 * 4) = o;
        float dx = x4.x - qx, dy = x4.y - qy, dz = x4.z - qz, dw = x4.w - qw;
        lloss += dx * dx + dy * dy + dz * dz + dw * dw;
    }
#pragma unroll
    for (int off = 32; off > 0; off >>= 1) lloss += __shfl_xor(lloss, off);
    if ((tid & 63) == 0) wls[tid >> 6] = lloss;
    __syncthreads();
    if (tid == 0) {
        float s = wls[0] + wls[1] + wls[2] + wls[3];
        atomicAdd(lossSum, s);
    }
}

__global__ __launch_bounds__(256) void finalize_kernel(const int* __restrict__ counts,
                                                       const float* __restrict__ lossSum,
                                                       float* __restrict__ out) {
    __shared__ float wls[4];
    int tid = threadIdx.x;
    float s = 0.f;
#pragma unroll
    for (int i = 0; i < 8; ++i) {
        int j = tid + i * 256;
        float p = (float)counts[j] * (1.0f / 65536.0f);
        s += p * logf(p + 1e-10f);
    }
#pragma unroll
    for (int off = 32; off > 0; off >>= 1) s += __shfl_xor(s, off);
    if ((tid & 63) == 0) wls[tid >> 6] = s;
    __syncthreads();
    if (tid == 0) {
        float tot = wls[0] + wls[1] + wls[2] + wls[3];
        float L = *lossSum * (1.0f / (float)QST_SIZE);
        out[QST_SIZE + 0] = 0.25f * L;   // commitment_loss
        out[QST_SIZE + 1] = L;           // codebook_loss
        out[QST_SIZE + 2] = expf(-tot);  // perplexity
    }
}

extern "C" void kernel_launch(void* const* d_in, const int* in_sizes, int n_in,
                              void* d_out, int out_size, void* d_ws, size_t ws_size,
                              hipStream_t stream) {
    const float* x    = (const float*)d_in[0];
    const float* emb  = (const float*)d_in[1];
    const float* mask = (const float*)d_in[2];
    float* out = (float*)d_out;

    _Float16* ehf  = (_Float16*)((char*)d_ws + WS_EH);
    _Float16* elf  = (_Float16*)((char*)d_ws + WS_EL);
    float* d0p     = (float*)((char*)d_ws + WS_D0);
    int*   counts  = (int*)((char*)d_ws + WS_CNT);
    float* lossSum = (float*)((char*)d_ws + WS_LOSS);

    prep_kernel<<<dim3(8), dim3(256), 0, stream>>>(emb, ehf, elf, d0p, counts, lossSum);
    vq_main<<<dim3(NTOK / TOK_TILE, NCB), dim3(256), 0, stream>>>(
        x, emb, mask, ehf, elf, d0p, counts, lossSum, out, out + IDX_OFF);
    finalize_kernel<<<dim3(1), dim3(256), 0, stream>>>(counts, lossSum, out);
}